// Round 2
// baseline (247.002 us; speedup 1.0000x reference)
//
#include <hip/hip_runtime.h>

#define N_TOTAL   16777216
#define NWIN      65536
#define NFFT      256
#define MIN_FREQS 202
#define MIN_TIMES 51773
#define NSLOTS    64

/* workspace layout (float indices) */
#define IDX_ABSMAX  0      /* uint bits, atomicMax */
#define IDX_TMAX    1      /* uint bits, atomicMax */
#define IDX_TCNT    2      /* int: time-mask popcount (atomicAdd) */
#define IDX_FMALL   3      /* int: 1 = freq mask all ones */
#define IDX_TTHR    4
#define IDX_INVNORM 5
#define IDX_FCNT    6
#define IDX_FMASK   8      /* 256 floats (DIF storage order = bit-reversed) */
#define IDX_SLOTS   264    /* 64*256 floats, freq-energy partial slots */
#define IDX_SUMSQ   16648  /* 65536 floats, per-window sum of squares */
#define IDX_TMASKA  82184  /* 65536 floats, time mask */

#define ANG (-0.024543692606170f)   /* -2*pi/256 */

/* cross-lane DIF butterfly: f = partner + sign*own ; v = f * (tr + i*ti) */
#define XPAIR(VR, VI, H, TR, TI, SG)                 \
  { float pr_ = __shfl_xor(VR, H);                   \
    float pi_ = __shfl_xor(VI, H);                   \
    float fr_ = fmaf(SG, VR, pr_);                   \
    float fi_ = fmaf(SG, VI, pi_);                   \
    VR = fr_ * (TR) - fi_ * (TI);                    \
    VI = fr_ * (TI) + fi_ * (TR); }

#define XSTAGE(H, TR, TI, SG)                        \
  XPAIR(v0r, v0i, H, TR, TI, SG)                     \
  XPAIR(v1r, v1i, H, TR, TI, SG)                     \
  XPAIR(v2r, v2i, H, TR, TI, SG)                     \
  XPAIR(v3r, v3i, H, TR, TI, SG)

#define XPAIR1(VR, VI, SG)                           \
  { float pr_ = __shfl_xor(VR, 1);                   \
    float pi_ = __shfl_xor(VI, 1);                   \
    VR = fmaf(SG, VR, pr_);                          \
    VI = fmaf(SG, VI, pi_); }

/* ---------------- K1: stats pass, wave-resident FFT (no LDS in hot loop) --- */
__global__ __launch_bounds__(256) void k_stats(const float* __restrict__ x,
                                               float* __restrict__ W)
{
    const int lane = threadIdx.x & 63;
    const int wid  = (blockIdx.x << 2) | (threadIdx.x >> 6);   /* 0..8191 */
    float* sumsq = W + IDX_SUMSQ;

    /* per-lane twiddle precompute */
    float sA, cA; __sincosf(ANG * (float)lane, &sA, &cA);          /* W[l]  */
    float sB, cB; __sincosf(ANG * (float)(2 * lane), &sB, &cB);    /* W[2l] */
    float t32r, t32i, s32, t16r, t16i, s16, t8r, t8i, s8;
    float t4r, t4i, s4, t2r, t2i, s2, s1;
    { bool b = lane & 32; float s, c; __sincosf(ANG * (float)((lane & 31) << 2), &s, &c);
      t32r = b ? c : 1.f; t32i = b ? s : 0.f; s32 = b ? -1.f : 1.f; }
    { bool b = lane & 16; float s, c; __sincosf(ANG * (float)((lane & 15) << 3), &s, &c);
      t16r = b ? c : 1.f; t16i = b ? s : 0.f; s16 = b ? -1.f : 1.f; }
    { bool b = lane & 8;  float s, c; __sincosf(ANG * (float)((lane & 7) << 4), &s, &c);
      t8r  = b ? c : 1.f; t8i  = b ? s : 0.f; s8  = b ? -1.f : 1.f; }
    { bool b = lane & 4;  float s, c; __sincosf(ANG * (float)((lane & 3) << 5), &s, &c);
      t4r  = b ? c : 1.f; t4i  = b ? s : 0.f; s4  = b ? -1.f : 1.f; }
    { bool b = lane & 2;  float s, c; __sincosf(ANG * (float)((lane & 1) << 6), &s, &c);
      t2r  = b ? c : 1.f; t2i  = b ? s : 0.f; s2  = b ? -1.f : 1.f; }
    s1 = (lane & 1) ? -1.f : 1.f;

    float f0 = 0.f, f1 = 0.f, f2 = 0.f, f3 = 0.f;
    float amax = 0.f, tmx = 0.f;
    const int wbase = wid * 8;

    for (int k = 0; k < 8; k++) {
        const int win = wbase + k;
        const float* xp = x + (size_t)win * 256 + lane;
        const float u0 = xp[0], u1 = xp[64], u2 = xp[128], u3 = xp[192];

        amax = fmaxf(amax, fmaxf(fmaxf(fabsf(u0), fabsf(u1)),
                                 fmaxf(fabsf(u2), fabsf(u3))));
        float ss = u0 * u0 + u1 * u1 + u2 * u2 + u3 * u3;
        ss += __shfl_xor(ss, 1);  ss += __shfl_xor(ss, 2);  ss += __shfl_xor(ss, 4);
        ss += __shfl_xor(ss, 8);  ss += __shfl_xor(ss, 16); ss += __shfl_xor(ss, 32);
        if (lane == 0) sumsq[win] = ss;
        tmx = fmaxf(tmx, ss);

        /* stage h=128 (real inputs): slots (0,2) tw=W[l]; (1,3) tw=W[l+64]=-i*W[l] */
        const float d02 = u0 - u2, s02 = u0 + u2;
        const float d13 = u1 - u3, s13 = u1 + u3;
        const float r0 = s02;                 /* imag 0 */
        const float r1 = s13;                 /* imag 0 */
        const float r2 = d02 * cA, i2 = d02 * sA;
        const float r3 = d13 * sA, i3 = -d13 * cA;
        /* stage h=64: pairs (0,1),(2,3), tw=W[2l] */
        float v0r = r0 + r1,              v0i = 0.f;
        const float t1 = r0 - r1;
        float v1r = t1 * cB,              v1i = t1 * sB;
        float v2r = r2 + r3,              v2i = i2 + i3;
        const float t3r = r2 - r3,        t3i = i2 - i3;
        float v3r = t3r * cB - t3i * sB,  v3i = t3r * sB + t3i * cB;
        /* cross-lane stages */
        XSTAGE(32, t32r, t32i, s32)
        XSTAGE(16, t16r, t16i, s16)
        XSTAGE(8,  t8r,  t8i,  s8)
        XSTAGE(4,  t4r,  t4i,  s4)
        XSTAGE(2,  t2r,  t2i,  s2)
        XPAIR1(v0r, v0i, s1) XPAIR1(v1r, v1i, s1)
        XPAIR1(v2r, v2i, s1) XPAIR1(v3r, v3i, s1)

        f0 = fmaf(v0r, v0r, fmaf(v0i, v0i, f0));
        f1 = fmaf(v1r, v1r, fmaf(v1i, v1i, f1));
        f2 = fmaf(v2r, v2r, fmaf(v2i, v2i, f2));
        f3 = fmaf(v3r, v3r, fmaf(v3i, v3i, f3));
    }

    /* block-combine freq energies: LDS atomic add, then 1 global atomic/thread */
    __shared__ float sE[256];
    sE[threadIdx.x] = 0.f;
    __syncthreads();
    atomicAdd(&sE[lane      ], f0);
    atomicAdd(&sE[lane +  64], f1);
    atomicAdd(&sE[lane + 128], f2);
    atomicAdd(&sE[lane + 192], f3);
    __syncthreads();
    atomicAdd(&W[IDX_SLOTS + (size_t)(blockIdx.x & (NSLOTS - 1)) * 256 + threadIdx.x],
              sE[threadIdx.x]);

    amax = fmaxf(amax, __shfl_xor(amax, 1));
    amax = fmaxf(amax, __shfl_xor(amax, 2));
    amax = fmaxf(amax, __shfl_xor(amax, 4));
    amax = fmaxf(amax, __shfl_xor(amax, 8));
    amax = fmaxf(amax, __shfl_xor(amax, 16));
    amax = fmaxf(amax, __shfl_xor(amax, 32));
    if (lane == 0) {
        atomicMax((unsigned int*)W + IDX_ABSMAX, __float_as_uint(amax));
        atomicMax((unsigned int*)W + IDX_TMAX,   __float_as_uint(tmx));
    }
}

/* ---------------- K2: freq mask / flags / norm (single small block) -------- */
__global__ __launch_bounds__(256) void k_masks(float* __restrict__ W)
{
    __shared__ float e[256];
    __shared__ float red[256];
    const int tid = threadIdx.x;
    float acc = 0.f;
    #pragma unroll
    for (int s = 0; s < NSLOTS; s++) acc += W[IDX_SLOTS + s * 256 + tid];
    e[tid] = acc;
    red[tid] = acc; __syncthreads();
    for (int s = 128; s > 0; s >>= 1) {
        if (tid < s) red[tid] = fmaxf(red[tid], red[tid + s]);
        __syncthreads();
    }
    const float fthr = 0.05f * red[0];
    __syncthreads();
    const int my = (acc > fthr) ? 1 : 0;
    red[tid] = (float)my; __syncthreads();
    for (int s = 128; s > 0; s >>= 1) {
        if (tid < s) red[tid] += red[tid + s];
        __syncthreads();
    }
    const int fcnt = (int)red[0];
    __syncthreads();
    float m;
    if (fcnt >= MIN_FREQS) {
        m = (float)my;
    } else {
        /* exact top-k; ties broken by ORIGINAL freq index (storage is brev) */
        const int oi = (int)(__brev((unsigned)tid) >> 24);
        int rank = 0;
        for (int j = 0; j < 256; j++) {
            const float ej = e[j];
            const int oj = (int)(__brev((unsigned)j) >> 24);
            if (ej > acc || (ej == acc && oj < oi)) rank++;
        }
        m = (rank < MIN_FREQS) ? 1.f : 0.f;
    }
    W[IDX_FMASK + tid] = m;
    red[tid] = m; __syncthreads();
    for (int s = 128; s > 0; s >>= 1) {
        if (tid < s) red[tid] += red[tid + s];
        __syncthreads();
    }
    if (tid == 0) {
        ((int*)W)[IDX_FMALL] = ((int)red[0] == 256) ? 1 : 0;
        ((int*)W)[IDX_FCNT]  = fcnt;
        const float mx = __uint_as_float(((unsigned int*)W)[IDX_ABSMAX]);
        W[IDX_INVNORM] = 1.f / ((mx > 1e-10f) ? mx : 1.f);
        const float tmax = __uint_as_float(((unsigned int*)W)[IDX_TMAX]);
        W[IDX_TTHR] = 0.05f * tmax;
    }
}

/* ---------------- K2t: time threshold mask + count (parallel) -------------- */
__global__ __launch_bounds__(256) void k_tmask(float* __restrict__ W)
{
    const float tthr = W[IDX_TTHR];
    const float* sumsq = W + IDX_SUMSQ;
    float* tmask = W + IDX_TMASKA;
    const int base = blockIdx.x * 1024 + threadIdx.x;
    int c = 0;
    #pragma unroll
    for (int k = 0; k < 4; k++) {
        const int i = base + k * 256;
        const int mm = (sumsq[i] > tthr) ? 1 : 0;
        c += mm;
        tmask[i] = (float)mm;
    }
    c += __shfl_xor(c, 1);  c += __shfl_xor(c, 2);  c += __shfl_xor(c, 4);
    c += __shfl_xor(c, 8);  c += __shfl_xor(c, 16); c += __shfl_xor(c, 32);
    if ((threadIdx.x & 63) == 0) atomicAdd((int*)W + IDX_TCNT, c);
}

/* ---------------- K2b: exact time top-k fallback (early-exit normally) ----- */
__global__ __launch_bounds__(256) void k_timefb(float* __restrict__ W)
{
    if (((const int*)W)[IDX_TCNT] >= MIN_TIMES) return;
    const int t = blockIdx.x * 256 + threadIdx.x;
    const float* sumsq = W + IDX_SUMSQ;
    const float st = sumsq[t];
    int rank = 0;
    for (int j = 0; j < NWIN; j++) {
        const float sj = sumsq[j];
        if (sj > st || (sj == st && j < t)) rank++;
    }
    W[IDX_TMASKA + t] = (rank < MIN_TIMES) ? 1.f : 0.f;
}

/* ---------------- K3: output pass ------------------------------------------ */
__global__ __launch_bounds__(256) void k_out(const float* __restrict__ x,
                                             float* __restrict__ out,
                                             const float* __restrict__ W)
{
    const int tid = threadIdx.x;
    const int fm_all = ((const int*)W)[IDX_FMALL];
    const float inv_norm = W[IDX_INVNORM];
    if (fm_all) {
        /* ifft(fft(x) * 1) == x : masked scaled copy, float4 */
        const float4* xi = (const float4*)x;
        float4* yo = (float4*)out;
        const float* tmask = W + IDX_TMASKA;
        for (int i = blockIdx.x * 256 + tid; i < N_TOTAL / 4; i += gridDim.x * 256) {
            const float s = inv_norm * tmask[i >> 6];
            float4 v = xi[i];
            v.x *= s; v.y *= s; v.z *= s; v.w *= s;
            yo[i] = v;
        }
        return;
    }
    /* general path: FFT -> freq mask -> IFFT per window (LDS, correctness path) */
    __shared__ float re[256], im[256], twr[128], twi[128], fm[256];
    if (tid < 128) {
        float s, c;
        __sincosf(-6.283185307179586f * (float)tid / 256.0f, &s, &c);
        twr[tid] = c; twi[tid] = s;
    }
    fm[tid] = W[IDX_FMASK + tid];
    __syncthreads();
    const float scale = inv_norm * (1.f / 256.f);
    for (int w = blockIdx.x; w < NWIN; w += gridDim.x) {
        const float tm = W[IDX_TMASKA + w];
        if (tm == 0.f) { out[w * 256 + tid] = 0.f; continue; }
        re[tid] = x[w * 256 + tid]; im[tid] = 0.f;
        __syncthreads();
        for (int lh = 7; lh >= 0; lh--) {              /* DIF forward */
            const int half = 1 << lh;
            if (tid < 128) {
                const int k  = tid & (half - 1);
                const int i0 = ((tid & ~(half - 1)) << 1) | k;
                const int i1 = i0 + half;
                const float ar = re[i0], ai = im[i0], br = re[i1], bi = im[i1];
                const float dr = ar - br, di = ai - bi;
                re[i0] = ar + br; im[i0] = ai + bi;
                const int ti = k << (7 - lh);
                const float wr = twr[ti], wi = twi[ti];
                re[i1] = dr * wr - di * wi;
                im[i1] = dr * wi + di * wr;
            }
            __syncthreads();
        }
        re[tid] *= fm[tid]; im[tid] *= fm[tid];
        __syncthreads();
        for (int lh = 0; lh < 8; lh++) {               /* DIT inverse (conj) */
            const int half = 1 << lh;
            if (tid < 128) {
                const int k  = tid & (half - 1);
                const int i0 = ((tid & ~(half - 1)) << 1) | k;
                const int i1 = i0 + half;
                const int ti = k << (7 - lh);
                const float wr = twr[ti], wi = -twi[ti];
                const float br = re[i1], bi = im[i1];
                const float tr = br * wr - bi * wi;
                const float ts = br * wi + bi * wr;
                const float ar = re[i0], ai = im[i0];
                re[i1] = ar - tr; im[i1] = ai - ts;
                re[i0] = ar + tr; im[i0] = ai + ts;
            }
            __syncthreads();
        }
        out[w * 256 + tid] = re[tid] * scale;
        __syncthreads();
    }
}

extern "C" void kernel_launch(void* const* d_in, const int* in_sizes, int n_in,
                              void* d_out, int out_size, void* d_ws, size_t ws_size,
                              hipStream_t stream)
{
    const float* x = (const float*)d_in[0];
    float* out = (float*)d_out;
    float* W = (float*)d_ws;
    /* zero atomic accumulators + flags + freq slots */
    hipMemsetAsync(d_ws, 0, (size_t)IDX_SUMSQ * sizeof(float), stream);
    hipLaunchKernelGGL(k_stats,  dim3(2048), dim3(256), 0, stream, x, W);
    hipLaunchKernelGGL(k_masks,  dim3(1),    dim3(256), 0, stream, W);
    hipLaunchKernelGGL(k_tmask,  dim3(64),   dim3(256), 0, stream, W);
    hipLaunchKernelGGL(k_timefb, dim3(256),  dim3(256), 0, stream, W);
    hipLaunchKernelGGL(k_out,    dim3(2048), dim3(256), 0, stream, x, out, W);
}

// Round 3
// 153.267 us; speedup vs baseline: 1.6116x; 1.6116x over previous
//
#include <hip/hip_runtime.h>

#define N_TOTAL   16777216
#define NWIN      65536
#define MIN_FREQS 202
#define MIN_TIMES 51773
#define NSLOTS    64

/* workspace layout (float indices) */
#define IDX_ABSMAX  0      /* uint bits, atomicMax */
#define IDX_TMAX    1      /* uint bits, atomicMax */
#define IDX_TCNT    2      /* int: time-mask popcount (atomicAdd) */
#define IDX_FMALL   3      /* int: 1 = freq mask all ones */
#define IDX_TTHR    4
#define IDX_INVNORM 5
#define IDX_FCNT    6
#define IDX_FMASK   8      /* 256 floats, NATURAL frequency order */
#define IDX_SLOTS   264    /* 64*256 floats, freq-energy partial slots */
#define IDX_SUMSQ   16648  /* 65536 floats, per-window sum of squares */
#define IDX_TMASKA  82184  /* 65536 floats, time mask */

/* in-register 16-point FFT, natural in -> natural out (DIT, brev first).
   All indices compile-time after unroll -> stays in VGPRs. */
__device__ __forceinline__ void fft16(float ar[16], float ai[16])
{
#define SWP(a,b) { float t_=ar[a]; ar[a]=ar[b]; ar[b]=t_; \
                   t_=ai[a]; ai[a]=ai[b]; ai[b]=t_; }
    SWP(1,8) SWP(2,4) SWP(3,12) SWP(5,10) SWP(7,14) SWP(11,13)
#undef SWP
    /* stage len=2 */
#pragma unroll
    for (int i = 0; i < 16; i += 2) {
        float tr = ar[i+1], ti = ai[i+1];
        ar[i+1] = ar[i] - tr; ai[i+1] = ai[i] - ti;
        ar[i] += tr;          ai[i] += ti;
    }
    /* stage len=4 : tw {1, -i} */
#pragma unroll
    for (int i = 0; i < 16; i += 4) {
        { float tr = ar[i+2], ti = ai[i+2];
          ar[i+2] = ar[i] - tr; ai[i+2] = ai[i] - ti; ar[i] += tr; ai[i] += ti; }
        { float tr = ai[i+3], ti = -ar[i+3];
          ar[i+3] = ar[i+1] - tr; ai[i+3] = ai[i+1] - ti; ar[i+1] += tr; ai[i+1] += ti; }
    }
    /* stage len=8 : tw W8^j = {1, (r,-r), -i, (-r,-r)}, r=sqrt(2)/2 */
#pragma unroll
    for (int i = 0; i < 16; i += 8) {
        { float tr = ar[i+4], ti = ai[i+4];
          ar[i+4] = ar[i] - tr; ai[i+4] = ai[i] - ti; ar[i] += tr; ai[i] += ti; }
        { float br = ar[i+5], bi = ai[i+5];
          float tr = 0.70710678f * (br + bi), ti = 0.70710678f * (bi - br);
          ar[i+5] = ar[i+1] - tr; ai[i+5] = ai[i+1] - ti; ar[i+1] += tr; ai[i+1] += ti; }
        { float tr = ai[i+6], ti = -ar[i+6];
          ar[i+6] = ar[i+2] - tr; ai[i+6] = ai[i+2] - ti; ar[i+2] += tr; ai[i+2] += ti; }
        { float br = ar[i+7], bi = ai[i+7];
          float tr = 0.70710678f * (bi - br), ti = -0.70710678f * (br + bi);
          ar[i+7] = ar[i+3] - tr; ai[i+7] = ai[i+3] - ti; ar[i+3] += tr; ai[i+3] += ti; }
    }
    /* stage len=16 : tw W16^j */
    { float tr = ar[8], ti = ai[8];
      ar[8] = ar[0] - tr; ai[8] = ai[0] - ti; ar[0] += tr; ai[0] += ti; }
#define BUT(J, WR, WI) { float br = ar[8+J], bi = ai[8+J];     \
      float tr = br*(WR) - bi*(WI), ti = br*(WI) + bi*(WR);    \
      ar[8+J] = ar[J] - tr; ai[8+J] = ai[J] - ti; ar[J] += tr; ai[J] += ti; }
    BUT(1,  0.92387953f, -0.38268343f)
    BUT(2,  0.70710678f, -0.70710678f)
    BUT(3,  0.38268343f, -0.92387953f)
    BUT(4,  0.f, -1.f)
    BUT(5, -0.38268343f, -0.92387953f)
    BUT(6, -0.70710678f, -0.70710678f)
    BUT(7, -0.92387953f, -0.38268343f)
#undef BUT
}

/* ---------------- K1: stats pass — four-step FFT (16x16), register-resident */
__global__ __launch_bounds__(256) void k_stats(const float* __restrict__ x,
                                               float* __restrict__ W)
{
    __shared__ float2 T[4352];   /* 4 waves * 4 windows * (16*17) complex */
    __shared__ float  sE[256];
    const int tid  = threadIdx.x;
    const int lane = tid & 63;
    const int wv   = tid >> 6;
    const int subw = (lane >> 4);       /* window within wave's 4 */
    const int n2   = lane & 15;         /* column index / later k1 */
    float2* Tw = T + wv * 1088 + subw * 272;

    float cs, sn;                        /* W256^{n2} */
    __sincosf(-0.024543692606170f * (float)n2, &sn, &cs);

    float e[16];
#pragma unroll
    for (int k = 0; k < 16; ++k) e[k] = 0.f;
    float amax = 0.f, tmx = 0.f;
    float* sumsq = W + IDX_SUMSQ;

    const int wave_gid = (blockIdx.x << 2) | wv;     /* 0..4095 */
    for (int g = wave_gid; g < NWIN / 4; g += 4096) {
        const float* xp = x + (size_t)g * 1024 + subw * 256 + n2;
        float ar[16], ai[16];
        float ss = 0.f;
#pragma unroll
        for (int j = 0; j < 16; ++j) {
            const float v = xp[j * 16];
            ar[j] = v; ai[j] = 0.f;
            ss = fmaf(v, v, ss);
            amax = fmaxf(amax, fabsf(v));
        }
        ss += __shfl_xor(ss, 1); ss += __shfl_xor(ss, 2);
        ss += __shfl_xor(ss, 4); ss += __shfl_xor(ss, 8);
        if (n2 == 0) sumsq[g * 4 + subw] = ss;
        tmx = fmaxf(tmx, ss);

        fft16(ar, ai);                         /* column FFT over n1 */

        /* twiddle W256^{n2*k1} via recurrence */
        { float wr = 1.f, wi = 0.f;
#pragma unroll
          for (int k = 1; k < 16; ++k) {
              const float nwr = wr * cs - wi * sn;
              const float nwi = wr * sn + wi * cs;
              wr = nwr; wi = nwi;
              const float xr = ar[k], xi = ai[k];
              ar[k] = xr * wr - xi * wi;
              ai[k] = xr * wi + xi * wr;
          } }

        /* 16x16 transpose through LDS (stride 17 = bank-optimal) */
#pragma unroll
        for (int k = 0; k < 16; ++k)
            Tw[k * 17 + n2] = make_float2(ar[k], ai[k]);
        asm volatile("s_waitcnt lgkmcnt(0)" ::: "memory");
        __builtin_amdgcn_wave_barrier();
#pragma unroll
        for (int k = 0; k < 16; ++k) {
            const float2 t = Tw[n2 * 17 + k];   /* lane now plays role k1=n2 */
            ar[k] = t.x; ai[k] = t.y;
        }
        asm volatile("s_waitcnt lgkmcnt(0)" ::: "memory");
        __builtin_amdgcn_wave_barrier();

        fft16(ar, ai);                         /* row FFT over n2 -> X[16k2+k1] */
#pragma unroll
        for (int k = 0; k < 16; ++k)
            e[k] = fmaf(ar[k], ar[k], fmaf(ai[k], ai[k], e[k]));
    }

    /* block-combine freq energies (natural order bin = 16*k2 + k1) */
    sE[tid] = 0.f;
    __syncthreads();
#pragma unroll
    for (int k = 0; k < 16; ++k)
        atomicAdd(&sE[k * 16 + n2], e[k]);
    __syncthreads();
    atomicAdd(&W[IDX_SLOTS + (size_t)(blockIdx.x & (NSLOTS - 1)) * 256 + tid], sE[tid]);

    amax = fmaxf(amax, __shfl_xor(amax, 1));
    amax = fmaxf(amax, __shfl_xor(amax, 2));
    amax = fmaxf(amax, __shfl_xor(amax, 4));
    amax = fmaxf(amax, __shfl_xor(amax, 8));
    amax = fmaxf(amax, __shfl_xor(amax, 16));
    amax = fmaxf(amax, __shfl_xor(amax, 32));
    tmx = fmaxf(tmx, __shfl_xor(tmx, 16));
    tmx = fmaxf(tmx, __shfl_xor(tmx, 32));
    if (lane == 0) {
        atomicMax((unsigned int*)W + IDX_ABSMAX, __float_as_uint(amax));
        atomicMax((unsigned int*)W + IDX_TMAX,   __float_as_uint(tmx));
    }
}

/* ---------------- K2: freq mask / flags / norm (single small block) -------- */
__global__ __launch_bounds__(256) void k_masks(float* __restrict__ W)
{
    __shared__ float e[256];
    __shared__ float red[256];
    const int tid = threadIdx.x;
    float acc = 0.f;
#pragma unroll
    for (int s = 0; s < NSLOTS; s++) acc += W[IDX_SLOTS + s * 256 + tid];
    e[tid] = acc;
    red[tid] = acc; __syncthreads();
    for (int s = 128; s > 0; s >>= 1) {
        if (tid < s) red[tid] = fmaxf(red[tid], red[tid + s]);
        __syncthreads();
    }
    const float fthr = 0.05f * red[0];
    __syncthreads();
    const int my = (acc > fthr) ? 1 : 0;
    red[tid] = (float)my; __syncthreads();
    for (int s = 128; s > 0; s >>= 1) {
        if (tid < s) red[tid] += red[tid + s];
        __syncthreads();
    }
    const int fcnt = (int)red[0];
    __syncthreads();
    float m;
    if (fcnt >= MIN_FREQS) {
        m = (float)my;
    } else {
        /* exact top-k; NATURAL order, ties by lower index */
        int rank = 0;
        for (int j = 0; j < 256; j++) {
            const float ej = e[j];
            if (ej > acc || (ej == acc && j < tid)) rank++;
        }
        m = (rank < MIN_FREQS) ? 1.f : 0.f;
    }
    W[IDX_FMASK + tid] = m;
    red[tid] = m; __syncthreads();
    for (int s = 128; s > 0; s >>= 1) {
        if (tid < s) red[tid] += red[tid + s];
        __syncthreads();
    }
    if (tid == 0) {
        ((int*)W)[IDX_FMALL] = ((int)red[0] == 256) ? 1 : 0;
        ((int*)W)[IDX_FCNT]  = fcnt;
        const float mx = __uint_as_float(((unsigned int*)W)[IDX_ABSMAX]);
        W[IDX_INVNORM] = 1.f / ((mx > 1e-10f) ? mx : 1.f);
        const float tmax = __uint_as_float(((unsigned int*)W)[IDX_TMAX]);
        W[IDX_TTHR] = 0.05f * tmax;
    }
}

/* ---------------- K2t: time threshold mask + count (parallel) -------------- */
__global__ __launch_bounds__(256) void k_tmask(float* __restrict__ W)
{
    const float tthr = W[IDX_TTHR];
    const float* sumsq = W + IDX_SUMSQ;
    float* tmask = W + IDX_TMASKA;
    const int base = blockIdx.x * 1024 + threadIdx.x;
    int c = 0;
#pragma unroll
    for (int k = 0; k < 4; k++) {
        const int i = base + k * 256;
        const int mm = (sumsq[i] > tthr) ? 1 : 0;
        c += mm;
        tmask[i] = (float)mm;
    }
    c += __shfl_xor(c, 1);  c += __shfl_xor(c, 2);  c += __shfl_xor(c, 4);
    c += __shfl_xor(c, 8);  c += __shfl_xor(c, 16); c += __shfl_xor(c, 32);
    if ((threadIdx.x & 63) == 0) atomicAdd((int*)W + IDX_TCNT, c);
}

/* ---------------- K2b: exact time top-k fallback (early-exit normally) ----- */
__global__ __launch_bounds__(256) void k_timefb(float* __restrict__ W)
{
    if (((const int*)W)[IDX_TCNT] >= MIN_TIMES) return;
    const int t = blockIdx.x * 256 + threadIdx.x;
    const float* sumsq = W + IDX_SUMSQ;
    const float st = sumsq[t];
    int rank = 0;
    for (int j = 0; j < NWIN; j++) {
        const float sj = sumsq[j];
        if (sj > st || (sj == st && j < t)) rank++;
    }
    W[IDX_TMASKA + t] = (rank < MIN_TIMES) ? 1.f : 0.f;
}

/* ---------------- K3: output pass ------------------------------------------ */
__global__ __launch_bounds__(256) void k_out(const float* __restrict__ x,
                                             float* __restrict__ out,
                                             const float* __restrict__ W)
{
    const int tid = threadIdx.x;
    const int fm_all = ((const int*)W)[IDX_FMALL];
    const float inv_norm = W[IDX_INVNORM];
    if (fm_all) {
        /* ifft(fft(x) * 1) == x : masked scaled copy, float4 */
        const float4* xi = (const float4*)x;
        float4* yo = (float4*)out;
        const float* tmask = W + IDX_TMASKA;
        for (int i = blockIdx.x * 256 + tid; i < N_TOTAL / 4; i += gridDim.x * 256) {
            const float s = inv_norm * tmask[i >> 6];
            float4 v = xi[i];
            v.x *= s; v.y *= s; v.z *= s; v.w *= s;
            yo[i] = v;
        }
        return;
    }
    /* general path: FFT -> freq mask -> IFFT per window (LDS, correctness path).
       DIF storage order is bit-reversed: mask lookup uses brev(tid). */
    __shared__ float re[256], im[256], twr[128], twi[128], fm[256];
    if (tid < 128) {
        float s, c;
        __sincosf(-6.283185307179586f * (float)tid / 256.0f, &s, &c);
        twr[tid] = c; twi[tid] = s;
    }
    fm[tid] = W[IDX_FMASK + (int)(__brev((unsigned)tid) >> 24)];
    __syncthreads();
    const float scale = inv_norm * (1.f / 256.f);
    for (int w = blockIdx.x; w < NWIN; w += gridDim.x) {
        const float tm = W[IDX_TMASKA + w];
        if (tm == 0.f) { out[w * 256 + tid] = 0.f; continue; }
        re[tid] = x[w * 256 + tid]; im[tid] = 0.f;
        __syncthreads();
        for (int lh = 7; lh >= 0; lh--) {              /* DIF forward */
            const int half = 1 << lh;
            if (tid < 128) {
                const int k  = tid & (half - 1);
                const int i0 = ((tid & ~(half - 1)) << 1) | k;
                const int i1 = i0 + half;
                const float ar = re[i0], ai = im[i0], br = re[i1], bi = im[i1];
                const float dr = ar - br, di = ai - bi;
                re[i0] = ar + br; im[i0] = ai + bi;
                const int ti = k << (7 - lh);
                const float wr = twr[ti], wi = twi[ti];
                re[i1] = dr * wr - di * wi;
                im[i1] = dr * wi + di * wr;
            }
            __syncthreads();
        }
        re[tid] *= fm[tid]; im[tid] *= fm[tid];
        __syncthreads();
        for (int lh = 0; lh < 8; lh++) {               /* DIT inverse (conj) */
            const int half = 1 << lh;
            if (tid < 128) {
                const int k  = tid & (half - 1);
                const int i0 = ((tid & ~(half - 1)) << 1) | k;
                const int i1 = i0 + half;
                const int ti = k << (7 - lh);
                const float wr = twr[ti], wi = -twi[ti];
                const float br = re[i1], bi = im[i1];
                const float tr = br * wr - bi * wi;
                const float ts = br * wi + bi * wr;
                const float ar = re[i0], ai = im[i0];
                re[i1] = ar - tr; im[i1] = ai - ts;
                re[i0] = ar + tr; im[i0] = ai + ts;
            }
            __syncthreads();
        }
        out[w * 256 + tid] = re[tid] * scale;
        __syncthreads();
    }
}

extern "C" void kernel_launch(void* const* d_in, const int* in_sizes, int n_in,
                              void* d_out, int out_size, void* d_ws, size_t ws_size,
                              hipStream_t stream)
{
    const float* x = (const float*)d_in[0];
    float* out = (float*)d_out;
    float* W = (float*)d_ws;
    /* zero atomic accumulators + flags + freq slots */
    hipMemsetAsync(d_ws, 0, (size_t)IDX_SUMSQ * sizeof(float), stream);
    hipLaunchKernelGGL(k_stats,  dim3(1024), dim3(256), 0, stream, x, W);
    hipLaunchKernelGGL(k_masks,  dim3(1),    dim3(256), 0, stream, W);
    hipLaunchKernelGGL(k_tmask,  dim3(64),   dim3(256), 0, stream, W);
    hipLaunchKernelGGL(k_timefb, dim3(256),  dim3(256), 0, stream, W);
    hipLaunchKernelGGL(k_out,    dim3(2048), dim3(256), 0, stream, x, out, W);
}